// Round 10
// baseline (494.409 us; speedup 1.0000x reference)
//
#include <hip/hip_runtime.h>
#include <hip/hip_cooperative_groups.h>
#include <stdint.h>

namespace cg = cooperative_groups;

typedef unsigned int u32;
typedef unsigned long long u64;
typedef __attribute__((ext_vector_type(2))) unsigned long long u64x2;

#define BIMG 8
#define NPROP 4000
#define NCLS 91
#define CM1 90
#define MCAND (NPROP * CM1)      // 360000 candidates per image
#define KPRE 2048
#define NBUCKET 4096
#define NREP 8                   // counter replicas (contention /8)
#define SELCAP 16384
#define DETS 100
#define WLCAP 2048               // worklist capacity per image (max real ~1025)
#define SCORE_T 0.05f
#define NMS_T 0.5f
#define BBOX_CLIP 4.135166556742356f   // log(1000/16)

// ---------------- workspace layout (unchanged from r9) ----------------
#define HISTREP_OFF ((size_t)0)                                  // u32[8][8][4096] rep-major
#define BCNTREP_OFF (HISTREP_OFF + (size_t)NREP * BIMG * NBUCKET * 4)
#define META_OFF    (BCNTREP_OFF + (size_t)NREP * BIMG * NBUCKET * 4)  // u32[8][8]
#define ZERO_BYTES  (META_OFF + 4096)
#define START_OFF   (ZERO_BYTES)                                 // u32[8][4096]
#define HISTTOT_OFF (START_OFF + (size_t)BIMG * NBUCKET * 4)     // u32[8][4096]
#define STARTREP_OFF (HISTTOT_OFF + (size_t)BIMG * NBUCKET * 4)  // u32[8][8][4096]
#define SEL_OFF     (STARTREP_OFF + (size_t)NREP * BIMG * NBUCKET * 4) // u64[8][SELCAP]
#define TBOX_OFF    (SEL_OFF + (size_t)BIMG * SELCAP * 8)        // f32[8][2048][4]
#define TSB_OFF     (TBOX_OFF + (size_t)BIMG * KPRE * 16)        // f32[8][2048][4]
#define TSC_OFF     (TSB_OFF + (size_t)BIMG * KPRE * 16)         // f32[8][2048]
#define TLB_OFF     (TSC_OFF + (size_t)BIMG * KPRE * 4)          // i32[8][2048]
#define TVL_OFF     (TLB_OFF + (size_t)BIMG * KPRE * 4)          // u32[8][2048]
#define KEEP_OFF    (TVL_OFF + (size_t)BIMG * KPRE * 4)          // (unused now)
#define WLIST_OFF   (KEEP_OFF + (size_t)BIMG * 32 * 8)           // u32[8][WLCAP]
#define UNION_OFF   (WLIST_OFF + (size_t)BIMG * WLCAP * 4)       // cand_ord / mask overlay
#define UNION_BYTES ((size_t)BIMG * MCAND * 4)                   // 11.52 MB > mask's 4 MB
#define WS_NEED     (UNION_OFF + UNION_BYTES)                    // ~16.8 MB

#define ZW ((u32)(ZERO_BYTES / 4))       // u32 words to zero in P0
#define MW ((u32)(BIMG * KPRE * 32))     // u64 words of mask to zero in P4
#define NTHREADS 65536                   // 256 blocks x 256 threads

__device__ __forceinline__ void decode_clip(const float4 rg, const float w, const float h,
                                            const float cx, const float cy,
                                            const float fw, const float fh, float bx[4]) {
    float dx = rg.x / 10.0f;
    float dy = rg.y / 10.0f;
    float dw = fminf(rg.z / 5.0f, BBOX_CLIP);
    float dh = fminf(rg.w / 5.0f, BBOX_CLIP);
    float pcx = dx * w + cx;
    float pcy = dy * h + cy;
    float pw  = expf(dw) * w;
    float phh = expf(dh) * h;
    bx[0] = fminf(fmaxf(pcx - 0.5f * pw,  0.0f), fw);
    bx[1] = fminf(fmaxf(pcy - 0.5f * phh, 0.0f), fh);
    bx[2] = fminf(fmaxf(pcx + 0.5f * pw,  0.0f), fw);
    bx[3] = fminf(fmaxf(pcy + 0.5f * phh, 0.0f), fh);
}

__device__ __forceinline__ u64 rdlane64(u64 v, int l) {
    u32 lo = (u32)__builtin_amdgcn_readlane((int)(u32)v, l);
    u32 hi = (u32)__builtin_amdgcn_readlane((int)(u32)(v >> 32), l);
    return ((u64)hi << 32) | lo;
}

__device__ __forceinline__ void g2l16(const void* g, void* l) {
    __builtin_amdgcn_global_load_lds(
        (const __attribute__((address_space(1))) void*)g,
        (__attribute__((address_space(3))) void*)l, 16, 0, 0);
}

// One cooperative kernel, 256 blocks x 256 threads, 7 grid syncs.
// Phase algorithms identical to the r9 multi-kernel build (absmax 0);
// only work distribution (grid-stride) changed. k7+k8 fused (same wave).
__global__ __launch_bounds__(256) void mega(
    const float* __restrict__ logits, const float* __restrict__ reg,
    const float* __restrict__ props, const int* __restrict__ imh,
    const int* __restrict__ imw,
    u32* __restrict__ histrep, u32* __restrict__ bcntrep, u32* __restrict__ meta,
    u32* __restrict__ start, u32* __restrict__ histtot, u32* __restrict__ startrep,
    u64* __restrict__ sel, float* __restrict__ tbox, float* __restrict__ tsb,
    float* __restrict__ tsc, int* __restrict__ tlb, u32* __restrict__ tvl,
    u32* __restrict__ wlist, u32* cand_ord, u64* mask,
    float* __restrict__ out) {
    cg::grid_group grid = cg::this_grid();
    __shared__ u64 smem[4096];           // 32 KB: k4 bitonic arr / k7 double buffer
    __shared__ u32 s_wsum[4], s_qws[4], s_TbkS, s_Vs;
    __shared__ float s_wm[4];

    const int tid = threadIdx.x;
    const u32 gtid = blockIdx.x * 256u + (u32)tid;
    const int lane = tid & 63;

    // ================= P0: zero histrep + bcntrep + meta =================
    for (u32 i = gtid; i < ZW; i += NTHREADS) histrep[i] = 0u;
    grid.sync();

    // ================= P1: k1 score + histogram (one wave/proposal) ======
    {
        const int wid = (int)(gtid >> 6);          // 0..1023
        const float fw = (float)imw[0], fh = (float)imh[0];
        for (int pid = wid; pid < BIMG * NPROP; pid += NTHREADS / 64) {
            const int img = pid / NPROP;
            const float* lrow = logits + (size_t)pid * NCLS;
            float v0 = lrow[lane];
            float v1 = (lane < 27) ? lrow[lane + 64] : -3.0e38f;
            float mx = fmaxf(v0, v1);
#pragma unroll
            for (int o = 32; o > 0; o >>= 1) mx = fmaxf(mx, __shfl_xor(mx, o));
            float es = expf(v0 - mx) + ((lane < 27) ? expf(v1 - mx) : 0.0f);
#pragma unroll
            for (int o = 32; o > 0; o >>= 1) es += __shfl_xor(es, o);
            const float thr = mx + logf(es) - 2.9967323f;   // ln(0.05) - 1e-3 margin
            float4 p = reinterpret_cast<const float4*>(props)[pid];
            const float w = p.z - p.x, h = p.w - p.y;
            const float cx = p.x + 0.5f * w, cy = p.y + 0.5f * h;
            const float4* rrow = reinterpret_cast<const float4*>(reg) + (size_t)pid * NCLS;
            const int n = pid - img * NPROP;
            u32* co = cand_ord + (size_t)img * MCAND + (size_t)n * CM1;
#pragma unroll
            for (int batch = 0; batch < 2; ++batch) {
                int ci = lane + batch * 64;
                if (ci < CM1) {
                    int c = ci + 1;
                    float l = lrow[c];
                    u32 o = 0u;
                    if (l > thr) {                        // rare (~2% of lanes)
                        float sc = expf(l - mx) / es;     // exact
                        float4 rg = rrow[c];
                        float bx[4];
                        decode_clip(rg, w, h, cx, cy, fw, fh, bx);
                        bool valid = (sc > SCORE_T) && (bx[2] - bx[0] >= 1.0f) &&
                                     (bx[3] - bx[1] >= 1.0f);
                        if (valid) {
                            o = __float_as_uint(sc) | 0x80000000u;
                            u32 t = (u32)img * MCAND + (u32)n * CM1 + (u32)ci;
                            int rep = (int)((t >> 8) & (NREP - 1));
                            atomicAdd(&histrep[((size_t)rep * BIMG + img) * NBUCKET + (o >> 20)], 1u);
                        }
                    }
                    co[ci] = o;
                }
            }
        }
    }
    grid.sync();

    // ================= P2: k2 scan (blocks 0..7, one per image) ==========
    if (blockIdx.x < BIMG) {
        const int img = blockIdx.x;
        const int td = tid;
        const int wv = td >> 6;
        u32 cnt[16]; u32 tsum = 0;
#pragma unroll
        for (int k = 0; k < 16; ++k) {
            const int bk = NBUCKET - 1 - (td * 16 + k);
            u32 c = 0;
#pragma unroll
            for (int r = 0; r < NREP; ++r)
                c += histrep[((size_t)r * BIMG + img) * NBUCKET + bk];
            cnt[k] = c; tsum += c;
        }
        u32 inc = tsum;
#pragma unroll
        for (int o = 1; o < 64; o <<= 1) { u32 t = __shfl_up(inc, o); if (lane >= o) inc += t; }
        if (td == 0) s_TbkS = 0u;
        if (lane == 63) s_wsum[wv] = inc;
        __syncthreads();
        u32 wbase = 0;
        for (int i = 0; i < wv; ++i) wbase += s_wsum[i];
        if (td == 255) s_Vs = wbase + inc;
        const u32 excl0 = wbase + inc - tsum;
        u32 excl = excl0;
#pragma unroll
        for (int k = 0; k < 16; ++k) {
            const int bk = NBUCKET - 1 - (td * 16 + k);
            const u32 c = cnt[k];
            start[img * NBUCKET + bk] = excl;
            histtot[img * NBUCKET + bk] = c;
            u32 sub = excl;
#pragma unroll
            for (int r = 0; r < NREP; ++r) {
                startrep[((size_t)r * BIMG + img) * NBUCKET + bk] = sub;
                sub += histrep[((size_t)r * BIMG + img) * NBUCKET + bk];
            }
            if (c > 0 && excl < KPRE && excl + c >= KPRE) s_TbkS = (u32)bk;  // <=1 writer
            excl += c;
        }
        // worklist emission: buckets with cnt>=2 && start<KPRE
        u32 qcnt = 0;
        {
            u32 e = excl0;
#pragma unroll
            for (int k = 0; k < 16; ++k) { if (cnt[k] >= 2 && e < KPRE) ++qcnt; e += cnt[k]; }
        }
        u32 qinc = qcnt;
#pragma unroll
        for (int o = 1; o < 64; o <<= 1) { u32 t = __shfl_up(qinc, o); if (lane >= o) qinc += t; }
        if (lane == 63) s_qws[wv] = qinc;
        __syncthreads();
        u32 qbase = 0;
        for (int i = 0; i < wv; ++i) qbase += s_qws[i];
        u32 qoff = qbase + qinc - qcnt;
        {
            u32 e = excl0;
#pragma unroll
            for (int k = 0; k < 16; ++k) {
                const int bk = NBUCKET - 1 - (td * 16 + k);
                if (cnt[k] >= 2 && e < KPRE && qoff < WLCAP) wlist[img * WLCAP + (qoff++)] = (u32)bk;
                e += cnt[k];
            }
        }
        if (td == 255) meta[img * 8 + 3] = qbase + qinc;   // worklist count
        __syncthreads();
        if (td == 0) {
            u32 V = s_Vs;
            meta[img * 8 + 0] = V;
            meta[img * 8 + 1] = s_TbkS;
            meta[img * 8 + 2] = (V < KPRE) ? (KPRE - V) : 0u;
        }
    }
    grid.sync();

    // ================= P3: k3 compact (grid-stride) + k3b fill ===========
    {
        const u32 TOT = (u32)BIMG * (u32)MCAND;
        for (u32 t = gtid; t < TOT; t += NTHREADS) {
            const u32 o = cand_ord[t];
            if (!o) continue;
            const int img = (int)(t / (u32)MCAND);
            const u32 idx = t - (u32)img * (u32)MCAND;
            const u32 bk = o >> 20;
            if (bk < meta[img * 8 + 1]) continue;
            const int rep = (int)((t >> 8) & (NREP - 1));   // same key as r9
            const size_t ri = ((size_t)rep * BIMG + img) * NBUCKET + bk;
            const u32 pos = startrep[ri] + atomicAdd(&bcntrep[ri], 1u);
            if (pos < SELCAP)
                sel[(size_t)img * SELCAP + pos] = ((u64)o << 32) | (u32)(~idx);
        }
        // k3b (rare): blocks 0..7, wave 0; writes sel[V..) disjoint from k3
        if (blockIdx.x < BIMG && tid < 64) {
            const int img = blockIdx.x;
            const u32 need = meta[img * 8 + 2];
            if (need != 0) {
                const u32 V = meta[img * 8 + 0];
                const u32 ORDN1 = 0x407FFFFFu;  // ord_of(-1.0f)
                u32 filled = 0;
                for (u32 b0 = 0; b0 < MCAND && filled < need; b0 += 64) {
                    u32 idx = b0 + (u32)lane;
                    bool inv = (idx < MCAND) && (cand_ord[(size_t)img * MCAND + idx] == 0u);
                    u64 bal = __ballot(inv);
                    u32 pre = (u32)__popcll(bal & ((1ull << lane) - 1ull));
                    if (inv && (filled + pre) < need)
                        sel[(size_t)img * SELCAP + V + filled + pre] =
                            ((u64)ORDN1 << 32) | (u32)(~idx);
                    filled += (u32)__popcll(bal);
                }
            }
        }
    }
    grid.sync();

    // ====== P4: zero mask overlay (cand_ord now dead) + k4 bucket sorts ==
    {
        for (u32 i = gtid; i < MW; i += NTHREADS) mask[i] = 0ull;

        const int img = blockIdx.x & 7;
        const u32 wcount = meta[img * 8 + 3];
        u64* arr = smem;
        for (u32 wi = (u32)(blockIdx.x >> 3); wi < wcount; wi += 32) {
            const u32 bk = (wi < WLCAP) ? wlist[img * WLCAP + wi] : 0u;
            u32 cnt = histtot[img * NBUCKET + bk];       // uniform across block
            u32 st = start[img * NBUCKET + bk];
            if (cnt < 2 || st >= KPRE) continue;
            if (st + cnt > SELCAP) cnt = SELCAP - st;
            if (cnt > 4096) cnt = 4096;
            int n = 1;
            while (n < (int)cnt) n <<= 1;
            u64* seg = sel + (size_t)img * SELCAP + st;
            for (int i = tid; i < n; i += 256) arr[i] = (i < (int)cnt) ? seg[i] : 0ull;
            __syncthreads();
            for (int k = 2; k <= n; k <<= 1)
                for (int j = k >> 1; j > 0; j >>= 1) {
                    for (int i = tid; i < n; i += 256) {
                        int ixj = i ^ j;
                        if (ixj > i) {
                            u64 a = arr[i], b = arr[ixj];
                            bool swp = ((i & k) == 0) ? (a < b) : (a > b);
                            if (swp) { arr[i] = b; arr[ixj] = a; }
                        }
                    }
                    __syncthreads();
                }
            for (int i = tid; i < (int)cnt; i += 256) seg[i] = arr[i];
            __syncthreads();
        }
    }
    grid.sync();

    // ================= P5: k5 gather (blocks 0..7) =======================
    if (blockIdx.x < BIMG) {
        const int img = blockIdx.x;
        const float fw = (float)imw[0], fh = (float)imh[0];
        float bx[8][4];
        int lab[8];
        float lm = -3.0e38f;
#pragma unroll
        for (int t = 0; t < 8; ++t) {
            int s = t * 256 + tid;
            u64 key = sel[(size_t)img * SELCAP + s];
            u32 o = (u32)(key >> 32);
            u32 idx = ~((u32)key);
            u32 b = (o & 0x80000000u) ? (o & 0x7FFFFFFFu) : ~o;
            float sc = __uint_as_float(b);
            u32 n = idx / CM1;
            int c = (int)(idx - n * CM1) + 1;
            int pid = img * NPROP + (int)n;
            float4 p = reinterpret_cast<const float4*>(props)[pid];
            float w = p.z - p.x, h = p.w - p.y;
            float cx = p.x + 0.5f * w, cy = p.y + 0.5f * h;
            float4 rg = reinterpret_cast<const float4*>(reg)[(size_t)pid * NCLS + c];
            decode_clip(rg, w, h, cx, cy, fw, fh, bx[t]);
            lab[t] = c;
            lm = fmaxf(lm, fmaxf(fmaxf(bx[t][0], bx[t][1]), fmaxf(bx[t][2], bx[t][3])));
            reinterpret_cast<float4*>(tbox)[(size_t)img * KPRE + s] =
                make_float4(bx[t][0], bx[t][1], bx[t][2], bx[t][3]);
            tsc[(size_t)img * KPRE + s] = sc;
            tlb[(size_t)img * KPRE + s] = c;
            tvl[(size_t)img * KPRE + s] = (sc > SCORE_T) ? 1u : 0u;
        }
#pragma unroll
        for (int o2 = 32; o2 > 0; o2 >>= 1) lm = fmaxf(lm, __shfl_xor(lm, o2));
        if (lane == 0) s_wm[tid >> 6] = lm;
        __syncthreads();
        float mplus = fmaxf(fmaxf(s_wm[0], s_wm[1]), fmaxf(s_wm[2], s_wm[3])) + 1.0f;
#pragma unroll
        for (int t = 0; t < 8; ++t) {
            int s = t * 256 + tid;
            float off = (float)lab[t] * mplus;
            reinterpret_cast<float4*>(tsb)[(size_t)img * KPRE + s] =
                make_float4(bx[t][0] + off, bx[t][1] + off, bx[t][2] + off, bx[t][3] + off);
        }
    }
    grid.sync();

    // ====== P6: k6 IoU bitmask — shuffle-based, one wave per 64x64 tile,
    //        upper-triangle tiles only (lower supplied by P4's zeros) ======
    {
        const int wid = (int)(gtid >> 6);            // 0..1023
        for (int T = wid; T < BIMG * 528; T += NTHREADS / 64) {
            const int img = T / 528;
            int rem = T - img * 528;
            int by = 0;
            while (rem >= 32 - by) { rem -= (32 - by); ++by; }   // uniform per wave
            const int bx_ = by + rem;
            const int i0 = by * 64, j0 = bx_ * 64;
            const float4* tsb4 = reinterpret_cast<const float4*>(tsb) + (size_t)img * KPRE;
            float4 c = tsb4[j0 + lane];
            float cao = (c.z - c.x) * (c.w - c.y);
            float4 r = tsb4[i0 + lane];
            float ra = (r.z - r.x) * (r.w - r.y);
            const int i = i0 + lane;
            u64 bits = 0ull;
#pragma unroll 8
            for (int jj = 0; jj < 64; ++jj) {
                float ccx = __shfl(c.x, jj), ccy = __shfl(c.y, jj);
                float ccz = __shfl(c.z, jj), ccw = __shfl(c.w, jj);
                float caj = __shfl(cao, jj);
                float wv = fmaxf(fminf(r.z, ccz) - fmaxf(r.x, ccx), 0.0f);
                float hv = fmaxf(fminf(r.w, ccw) - fmaxf(r.y, ccy), 0.0f);
                float inter = wv * hv;
                float iou = inter / ((ra + caj) - inter);   // NaN compares false
                int j = j0 + jj;
                if ((iou > NMS_T) && (j > i)) bits |= (1ull << jj);
            }
            mask[((size_t)img * KPRE + i) * 32 + (j0 >> 6)] = bits;
        }
    }
    grid.sync();

    // ====== P7: k7 greedy NMS + k8 select, fused (same wave; blocks 0..7,
    //        wave 0). Algorithms identical to r9; keepw exchanged by shfl. ==
    if (blockIdx.x < BIMG && tid < 64) {
        const int img = blockIdx.x;
        const int lg = lane >> 4;
        const u64* mrow = mask + (size_t)img * KPRE * 32;

        u64 accx = 0ull, accy = 0ull, rp = 0ull;
        for (int w = 0; w < 32; ++w) {
            bool tv = tvl[(size_t)img * KPRE + w * 64 + lane] != 0u;
            u64 iw = ~__ballot(tv);
            if (w == 0) rp = iw;
            if ((lane & 15) == (w >> 1)) { if (w & 1) accy = iw; else accx = iw; }
        }

        {
            const char* gsrc = (const char*)mrow + (size_t)lane * 16;
#pragma unroll
            for (int t = 0; t < 16; ++t)
                g2l16(gsrc + (size_t)t * 1024, (char*)smem + (size_t)t * 1024);
        }
        u64 diag = mrow[(size_t)lane * 32];

        u32 tk = 0;
        int bcut = 31;

#pragma unroll 1
        for (int b = 0; b < 32; ++b) {
            const size_t base32 = (size_t)b * 2048;
            const u64* cbuf = smem + (size_t)(b & 1) * 2048;

            u64 diagn = 0ull;
            if (b + 1 < 32) {
                diagn = mrow[base32 + 2048 + (size_t)lane * 32 + (b + 1)];
                const char* gsrc = (const char*)(mrow + base32 + 2048) + (size_t)lane * 16;
                char* nb_l = (char*)(smem + (size_t)((b + 1) & 1) * 2048);
#pragma unroll
                for (int t = 0; t < 16; ++t)
                    g2l16(gsrc + (size_t)t * 1024, nb_l + (size_t)t * 1024);
            }

            u64 A = rp;
#pragma unroll
            for (int u = 0; u < 64; ++u) {
                u64 row = rdlane64(diag, u);
                if (!((A >> u) & 1ull)) A |= row;
            }
            const u64 keptw = ~A;

            if (b + 1 < 32) asm volatile("s_waitcnt vmcnt(17)" ::: "memory");
            else            asm volatile("s_waitcnt vmcnt(0)" ::: "memory");

#define LDV(K) u64x2 v##K = *(const u64x2*)&cbuf[128 * (K) + 2 * lane];
#define PRV(K) { u32 nib = (u32)(keptw >> (4 * (K))) & 15u; \
                 u32 kb = (nib >> lg) & 1u; \
                 accx |= kb ? v##K.x : 0ull; accy |= kb ? v##K.y : 0ull; }
            LDV(0) LDV(1) LDV(2) LDV(3)
            LDV(4) LDV(5) LDV(6) LDV(7)     PRV(0) PRV(1) PRV(2) PRV(3)
            LDV(8) LDV(9) LDV(10) LDV(11)   PRV(4) PRV(5) PRV(6) PRV(7)
            LDV(12) LDV(13) LDV(14) LDV(15) PRV(8) PRV(9) PRV(10) PRV(11)
            PRV(12) PRV(13) PRV(14) PRV(15)
#undef LDV
#undef PRV

            tk += (u32)__popcll(keptw);
            if (tk >= (u32)DETS) { bcut = b; break; }

            const int nb2 = b + 1;
            if (nb2 < 32) {
                u64 asel = (nb2 & 1) ? accy : accx;
                const int sl = (nb2 >> 1) & 15;
                rp = rdlane64(asel, sl) | rdlane64(asel, sl + 16) |
                     rdlane64(asel, sl + 32) | rdlane64(asel, sl + 48);
            }
            diag = diagn;
        }

        asm volatile("s_waitcnt vmcnt(0)" ::: "memory");   // drain in-flight DMA

        // merge 4-way partials; every lane then holds words 2(l&15), +1
        accx |= __shfl_xor(accx, 16); accx |= __shfl_xor(accx, 32);
        accy |= __shfl_xor(accy, 16); accy |= __shfl_xor(accy, 32);

        // ---- k8: lane w (<32) gets keep word w via shfl; gate by bcut ----
        u64 mxv = __shfl(accx, (lane >> 1) & 15);
        u64 myv = __shfl(accy, (lane >> 1) & 15);
        u64 kw = (lane & 1) ? ~myv : ~mxv;
        if (lane >= 32 || lane > bcut) kw = 0ull;

        u32 cnt = (u32)__popcll(kw);
        u32 inc = cnt;
#pragma unroll
        for (int o = 1; o < 64; o <<= 1) { u32 t = __shfl_up(inc, o); if (lane >= o) inc += t; }
        const u32 excl = inc - cnt;
        const u32 total = (u32)__shfl(inc, 63);

        float* ob0 = out + (size_t)img * DETS * 4;
        float* os0 = out + (size_t)BIMG * DETS * 4 + (size_t)img * DETS;
        float* ol0 = out + (size_t)BIMG * DETS * 5 + (size_t)img * DETS;

#pragma unroll
        for (int t = 0; t < 2; ++t) {
            u32 r = (u32)lane + (u32)t * 64;
            if (r < DETS && r >= total) {
                reinterpret_cast<float4*>(ob0)[r] = make_float4(0.f, 0.f, 0.f, 0.f);
                os0[r] = 0.0f;
                ol0[r] = -1.0f;
            }
        }
        u64 w = kw;
        u32 r = excl;
        while (w != 0ull && r < DETS) {
            int p = __ffsll((unsigned long long)w) - 1;
            w &= (w - 1ull);
            u32 s = (u32)lane * 64u + (u32)p;
            reinterpret_cast<float4*>(ob0)[r] =
                reinterpret_cast<const float4*>(tbox)[(size_t)img * KPRE + s];
            os0[r] = tsc[(size_t)img * KPRE + s];
            ol0[r] = (float)tlb[(size_t)img * KPRE + s];
            ++r;
        }
    }
}

extern "C" void kernel_launch(void* const* d_in, const int* in_sizes, int n_in,
                              void* d_out, int out_size, void* d_ws, size_t ws_size,
                              hipStream_t stream) {
    const float* logits = (const float*)d_in[0];
    const float* reg    = (const float*)d_in[1];
    const float* props  = (const float*)d_in[2];
    const int*   imh    = (const int*)d_in[3];
    const int*   imw    = (const int*)d_in[4];
    float* out = (float*)d_out;
    char* ws = (char*)d_ws;
    if (ws_size < WS_NEED) return;  // ~16.8 MB needed

    u32* histrep  = (u32*)(ws + HISTREP_OFF);
    u32* bcntrep  = (u32*)(ws + BCNTREP_OFF);
    u32* meta     = (u32*)(ws + META_OFF);
    u32* start    = (u32*)(ws + START_OFF);
    u32* histtot  = (u32*)(ws + HISTTOT_OFF);
    u32* startrep = (u32*)(ws + STARTREP_OFF);
    u64* sel  = (u64*)(ws + SEL_OFF);
    float* tbox = (float*)(ws + TBOX_OFF);
    float* tsb  = (float*)(ws + TSB_OFF);
    float* tsc  = (float*)(ws + TSC_OFF);
    int*   tlb  = (int*)(ws + TLB_OFF);
    u32*   tvl  = (u32*)(ws + TVL_OFF);
    u32*   wlist = (u32*)(ws + WLIST_OFF);
    u32*   cand_ord = (u32*)(ws + UNION_OFF);   // overlaid with mask (phase-separated)
    u64*   mask = (u64*)(ws + UNION_OFF);

    void* args[] = {
        (void*)&logits, (void*)&reg, (void*)&props, (void*)&imh, (void*)&imw,
        (void*)&histrep, (void*)&bcntrep, (void*)&meta, (void*)&start,
        (void*)&histtot, (void*)&startrep, (void*)&sel, (void*)&tbox,
        (void*)&tsb, (void*)&tsc, (void*)&tlb, (void*)&tvl, (void*)&wlist,
        (void*)&cand_ord, (void*)&mask, (void*)&out
    };
    hipLaunchCooperativeKernel((const void*)mega, dim3(256), dim3(256), args, 0, stream);
}

// Round 11
// 263.238 us; speedup vs baseline: 1.8782x; 1.8782x over previous
//
#include <hip/hip_runtime.h>
#include <stdint.h>

typedef unsigned int u32;
typedef unsigned long long u64;
typedef __attribute__((ext_vector_type(2))) unsigned long long u64x2;

#define BIMG 8
#define NPROP 4000
#define NCLS 91
#define CM1 90
#define MCAND (NPROP * CM1)      // 360000 candidates per image
#define KPRE 2048
#define NBUCKET 4096
#define NREP 8                   // counter replicas (contention /8)
#define SELCAP 16384
#define DETS 100
#define WLCAP 2048               // worklist capacity per image (max real ~1025)
#define SCORE_T 0.05f
#define NMS_T 0.5f
#define BBOX_CLIP 4.135166556742356f   // log(1000/16)

// ---------------- workspace layout (r9) ----------------
#define HISTREP_OFF ((size_t)0)                                  // u32[8][8][4096] rep-major
#define BCNTREP_OFF (HISTREP_OFF + (size_t)NREP * BIMG * NBUCKET * 4)
#define META_OFF    (BCNTREP_OFF + (size_t)NREP * BIMG * NBUCKET * 4)  // u32[8][8]
#define ZERO_BYTES  (META_OFF + 4096)
#define START_OFF   (ZERO_BYTES)                                 // u32[8][4096]
#define HISTTOT_OFF (START_OFF + (size_t)BIMG * NBUCKET * 4)     // u32[8][4096]
#define STARTREP_OFF (HISTTOT_OFF + (size_t)BIMG * NBUCKET * 4)  // u32[8][8][4096]
#define SEL_OFF     (STARTREP_OFF + (size_t)NREP * BIMG * NBUCKET * 4) // u64[8][SELCAP]
#define TBOX_OFF    (SEL_OFF + (size_t)BIMG * SELCAP * 8)        // f32[8][2048][4]
#define TSB_OFF     (TBOX_OFF + (size_t)BIMG * KPRE * 16)        // f32[8][2048][4]
#define TSC_OFF     (TSB_OFF + (size_t)BIMG * KPRE * 16)         // f32[8][2048]
#define TLB_OFF     (TSC_OFF + (size_t)BIMG * KPRE * 4)          // i32[8][2048]
#define TVL_OFF     (TLB_OFF + (size_t)BIMG * KPRE * 4)          // u32[8][2048]
#define KEEP_OFF    (TVL_OFF + (size_t)BIMG * KPRE * 4)          // (unused)
#define WLIST_OFF   (KEEP_OFF + (size_t)BIMG * 32 * 8)           // u32[8][WLCAP]
// UNION: cand_ord (dead after k3) overlays mask (fully written by k6 incl.
// sub-diagonal zero tiles — no memset needed). Same stream => ordered.
#define UNION_OFF   (WLIST_OFF + (size_t)BIMG * WLCAP * 4)
#define UNION_BYTES ((size_t)BIMG * MCAND * 4)                   // 11.52 MB > mask's 4 MB
#define WS_NEED     (UNION_OFF + UNION_BYTES)                    // ~16.8 MB

__device__ __forceinline__ void decode_clip(const float4 rg, const float w, const float h,
                                            const float cx, const float cy,
                                            const float fw, const float fh, float bx[4]) {
    float dx = rg.x / 10.0f;
    float dy = rg.y / 10.0f;
    float dw = fminf(rg.z / 5.0f, BBOX_CLIP);
    float dh = fminf(rg.w / 5.0f, BBOX_CLIP);
    float pcx = dx * w + cx;
    float pcy = dy * h + cy;
    float pw  = expf(dw) * w;
    float phh = expf(dh) * h;
    bx[0] = fminf(fmaxf(pcx - 0.5f * pw,  0.0f), fw);
    bx[1] = fminf(fmaxf(pcy - 0.5f * phh, 0.0f), fh);
    bx[2] = fminf(fmaxf(pcx + 0.5f * pw,  0.0f), fw);
    bx[3] = fminf(fmaxf(pcy + 0.5f * phh, 0.0f), fh);
}

// K1: one wave per proposal row (r9 verbatim).
__global__ __launch_bounds__(256) void k1_score_hist(
    const float* __restrict__ logits, const float* __restrict__ reg,
    const float* __restrict__ props, const int* __restrict__ imh, const int* __restrict__ imw,
    u32* __restrict__ histrep, u32* __restrict__ cand_ord) {
    const int lane = threadIdx.x & 63;
    const int pid = blockIdx.x * 4 + (threadIdx.x >> 6);
    if (pid >= BIMG * NPROP) return;
    const int img = pid / NPROP;
    const float fw = (float)imw[0], fh = (float)imh[0];
    const float* lrow = logits + (size_t)pid * NCLS;
    float v0 = lrow[lane];
    float v1 = (lane < 27) ? lrow[lane + 64] : -3.0e38f;
    float mx = fmaxf(v0, v1);
#pragma unroll
    for (int o = 32; o > 0; o >>= 1) mx = fmaxf(mx, __shfl_xor(mx, o));
    float es = expf(v0 - mx) + ((lane < 27) ? expf(v1 - mx) : 0.0f);
#pragma unroll
    for (int o = 32; o > 0; o >>= 1) es += __shfl_xor(es, o);
    const float thr = mx + logf(es) - 2.9967323f;   // ln(0.05) - 1e-3 margin
    float4 p = reinterpret_cast<const float4*>(props)[pid];
    const float w = p.z - p.x, h = p.w - p.y;
    const float cx = p.x + 0.5f * w, cy = p.y + 0.5f * h;
    const float4* rrow = reinterpret_cast<const float4*>(reg) + (size_t)pid * NCLS;
    const int n = pid - img * NPROP;
    u32* co = cand_ord + (size_t)img * MCAND + (size_t)n * CM1;
#pragma unroll
    for (int batch = 0; batch < 2; ++batch) {
        int ci = lane + batch * 64;
        if (ci < CM1) {
            int c = ci + 1;
            float l = lrow[c];
            u32 o = 0u;
            if (l > thr) {                        // rare (~2% of lanes)
                float sc = expf(l - mx) / es;     // exact
                float4 rg = rrow[c];
                float bx[4];
                decode_clip(rg, w, h, cx, cy, fw, fh, bx);
                bool valid = (sc > SCORE_T) && (bx[2] - bx[0] >= 1.0f) && (bx[3] - bx[1] >= 1.0f);
                if (valid) {
                    o = __float_as_uint(sc) | 0x80000000u;  // sc > 0 always
                    u32 t = (u32)img * MCAND + (u32)n * CM1 + (u32)ci;
                    int rep = (int)((t >> 8) & (NREP - 1));
                    atomicAdd(&histrep[((size_t)rep * BIMG + img) * NBUCKET + (o >> 20)], 1u);
                }
            }
            co[ci] = o;
        }
    }
}

// K2: one 256-thread block per image (r9 verbatim).
__global__ __launch_bounds__(256) void k2_scan(
    const u32* __restrict__ histrep, u32* __restrict__ histtot,
    u32* __restrict__ start, u32* __restrict__ startrep, u32* __restrict__ meta,
    u32* __restrict__ wlist) {
    const int img = blockIdx.x;
    const int td = threadIdx.x;
    const int lane = td & 63, wv = td >> 6;
    u32 cnt[16]; u32 tsum = 0;
#pragma unroll
    for (int k = 0; k < 16; ++k) {
        const int bk = NBUCKET - 1 - (td * 16 + k);
        u32 c = 0;
#pragma unroll
        for (int r = 0; r < NREP; ++r)
            c += histrep[((size_t)r * BIMG + img) * NBUCKET + bk];
        cnt[k] = c; tsum += c;
    }
    u32 inc = tsum;
#pragma unroll
    for (int o = 1; o < 64; o <<= 1) { u32 t = __shfl_up(inc, o); if (lane >= o) inc += t; }
    __shared__ u32 wsum[4];
    __shared__ u32 TbkS, Vs;
    if (td == 0) TbkS = 0u;
    if (lane == 63) wsum[wv] = inc;
    __syncthreads();
    u32 wbase = 0;
    for (int i = 0; i < wv; ++i) wbase += wsum[i];
    if (td == 255) Vs = wbase + inc;
    const u32 excl0 = wbase + inc - tsum;
    u32 excl = excl0;
#pragma unroll
    for (int k = 0; k < 16; ++k) {
        const int bk = NBUCKET - 1 - (td * 16 + k);
        const u32 c = cnt[k];
        start[img * NBUCKET + bk] = excl;
        histtot[img * NBUCKET + bk] = c;
        u32 sub = excl;
#pragma unroll
        for (int r = 0; r < NREP; ++r) {
            startrep[((size_t)r * BIMG + img) * NBUCKET + bk] = sub;
            sub += histrep[((size_t)r * BIMG + img) * NBUCKET + bk];
        }
        if (c > 0 && excl < KPRE && excl + c >= KPRE) TbkS = (u32)bk;  // <=1 writer
        excl += c;
    }
    u32 qcnt = 0;
    {
        u32 e = excl0;
#pragma unroll
        for (int k = 0; k < 16; ++k) { if (cnt[k] >= 2 && e < KPRE) ++qcnt; e += cnt[k]; }
    }
    u32 qinc = qcnt;
#pragma unroll
    for (int o = 1; o < 64; o <<= 1) { u32 t = __shfl_up(qinc, o); if (lane >= o) qinc += t; }
    __shared__ u32 qws[4];
    if (lane == 63) qws[wv] = qinc;
    __syncthreads();
    u32 qbase = 0;
    for (int i = 0; i < wv; ++i) qbase += qws[i];
    u32 qoff = qbase + qinc - qcnt;
    {
        u32 e = excl0;
#pragma unroll
        for (int k = 0; k < 16; ++k) {
            const int bk = NBUCKET - 1 - (td * 16 + k);
            if (cnt[k] >= 2 && e < KPRE && qoff < WLCAP) wlist[img * WLCAP + (qoff++)] = (u32)bk;
            e += cnt[k];
        }
    }
    if (td == 255) meta[img * 8 + 3] = qbase + qinc;   // worklist count
    __syncthreads();
    if (td == 0) {
        u32 V = Vs;
        meta[img * 8 + 0] = V;
        meta[img * 8 + 1] = TbkS;
        meta[img * 8 + 2] = (V < KPRE) ? (KPRE - V) : 0u;
    }
}

// K3: compact (r9) + k3b fill inlined in blocks 0..7 (sel[V..) disjoint
// from compacted [0..V) => no ordering needed; need==0 in practice).
__global__ __launch_bounds__(256) void k3_compact(
    const u32* __restrict__ cand_ord, const u32* __restrict__ startrep,
    const u32* __restrict__ meta, u32* __restrict__ bcntrep, u64* __restrict__ sel) {
    const u32 t = blockIdx.x * 256 + threadIdx.x;
    const int rep = (int)(blockIdx.x & (NREP - 1));   // == (t>>8)&7
    if (t < (u32)(BIMG * MCAND)) {
        const int img = t / MCAND;
        const u32 idx = t - (u32)img * MCAND;
        const u32 o = cand_ord[t];
        if (o) {
            const u32 bk = o >> 20;
            if (bk >= meta[img * 8 + 1]) {
                const size_t ri = ((size_t)rep * BIMG + img) * NBUCKET + bk;
                const u32 pos = startrep[ri] + atomicAdd(&bcntrep[ri], 1u);
                if (pos < SELCAP)
                    sel[(size_t)img * SELCAP + pos] = ((u64)o << 32) | (u32)(~idx);
            }
        }
    }
    // k3b rare path: blocks 0..7, wave 0
    if (blockIdx.x < BIMG && threadIdx.x < 64) {
        const int img = blockIdx.x;
        const u32 need = meta[img * 8 + 2];
        if (need != 0) {
            const u32 V = meta[img * 8 + 0];
            const int lane = threadIdx.x;
            const u32 ORDN1 = 0x407FFFFFu;  // ord_of(-1.0f)
            u32 filled = 0;
            for (u32 b0 = 0; b0 < MCAND && filled < need; b0 += 64) {
                u32 idx = b0 + (u32)lane;
                bool inv = (idx < MCAND) && (cand_ord[(size_t)img * MCAND + idx] == 0u);
                u64 bal = __ballot(inv);
                u32 pre = (u32)__popcll(bal & ((1ull << lane) - 1ull));
                if (inv && (filled + pre) < need)
                    sel[(size_t)img * SELCAP + V + filled + pre] =
                        ((u64)ORDN1 << 32) | (u32)(~idx);
                filled += (u32)__popcll(bal);
            }
        }
    }
}

// K4: worklist-driven bucket sorts (r9 verbatim).
__global__ __launch_bounds__(256) void k4_sortseg(
    const u32* __restrict__ histtot, const u32* __restrict__ start,
    const u32* __restrict__ meta, const u32* __restrict__ wlist, u64* __restrict__ sel) {
    __shared__ u64 arr[4096];
    const int img = blockIdx.y;
    const int tid = threadIdx.x;
    const u32 wcount = meta[img * 8 + 3];
    for (u32 wi = blockIdx.x; wi < wcount; wi += gridDim.x) {
        const u32 bk = (wi < WLCAP) ? wlist[img * WLCAP + wi] : 0u;
        u32 cnt = histtot[img * NBUCKET + bk];
        u32 st = start[img * NBUCKET + bk];
        if (cnt < 2 || st >= KPRE) continue;
        if (st + cnt > SELCAP) cnt = SELCAP - st;
        if (cnt > 4096) cnt = 4096;
        int n = 1;
        while (n < (int)cnt) n <<= 1;
        u64* seg = sel + (size_t)img * SELCAP + st;
        for (int i = tid; i < n; i += 256) arr[i] = (i < (int)cnt) ? seg[i] : 0ull;
        __syncthreads();
        for (int k = 2; k <= n; k <<= 1)
            for (int j = k >> 1; j > 0; j >>= 1) {
                for (int i = tid; i < n; i += 256) {
                    int ixj = i ^ j;
                    if (ixj > i) {
                        u64 a = arr[i], b = arr[ixj];
                        bool swp = ((i & k) == 0) ? (a < b) : (a > b);
                        if (swp) { arr[i] = b; arr[ixj] = a; }
                    }
                }
                __syncthreads();
            }
        for (int i = tid; i < (int)cnt; i += 256) seg[i] = arr[i];
        __syncthreads();
    }
}

// K5: gather top-2048 (r9 verbatim).
__global__ __launch_bounds__(256) void k5_gather(
    const u64* __restrict__ sel, const float* __restrict__ reg, const float* __restrict__ props,
    const int* __restrict__ imh, const int* __restrict__ imw,
    float* __restrict__ tbox, float* __restrict__ tsb, float* __restrict__ tsc,
    int* __restrict__ tlb, u32* __restrict__ tvl) {
    const int img = blockIdx.x;
    const int tid = threadIdx.x;
    const float fw = (float)imw[0], fh = (float)imh[0];
    float bx[8][4];
    int lab[8];
    float lm = -3.0e38f;
#pragma unroll
    for (int t = 0; t < 8; ++t) {
        int s = t * 256 + tid;
        u64 key = sel[(size_t)img * SELCAP + s];
        u32 o = (u32)(key >> 32);
        u32 idx = ~((u32)key);
        u32 b = (o & 0x80000000u) ? (o & 0x7FFFFFFFu) : ~o;
        float sc = __uint_as_float(b);               // exact masked score roundtrip
        u32 n = idx / CM1;
        int c = (int)(idx - n * CM1) + 1;
        int pid = img * NPROP + (int)n;
        float4 p = reinterpret_cast<const float4*>(props)[pid];
        float w = p.z - p.x, h = p.w - p.y;
        float cx = p.x + 0.5f * w, cy = p.y + 0.5f * h;
        float4 rg = reinterpret_cast<const float4*>(reg)[(size_t)pid * NCLS + c];
        decode_clip(rg, w, h, cx, cy, fw, fh, bx[t]);
        lab[t] = c;
        lm = fmaxf(lm, fmaxf(fmaxf(bx[t][0], bx[t][1]), fmaxf(bx[t][2], bx[t][3])));
        reinterpret_cast<float4*>(tbox)[(size_t)img * KPRE + s] =
            make_float4(bx[t][0], bx[t][1], bx[t][2], bx[t][3]);
        tsc[(size_t)img * KPRE + s] = sc;
        tlb[(size_t)img * KPRE + s] = c;
        tvl[(size_t)img * KPRE + s] = (sc > SCORE_T) ? 1u : 0u;
    }
#pragma unroll
    for (int o2 = 32; o2 > 0; o2 >>= 1) lm = fmaxf(lm, __shfl_xor(lm, o2));
    __shared__ float wm[4];
    if ((tid & 63) == 0) wm[tid >> 6] = lm;
    __syncthreads();
    float mplus = fmaxf(fmaxf(wm[0], wm[1]), fmaxf(wm[2], wm[3])) + 1.0f;
#pragma unroll
    for (int t = 0; t < 8; ++t) {
        int s = t * 256 + tid;
        float off = (float)lab[t] * mplus;
        reinterpret_cast<float4*>(tsb)[(size_t)img * KPRE + s] =
            make_float4(bx[t][0] + off, bx[t][1] + off, bx[t][2] + off, bx[t][3] + off);
    }
}

// K6: IoU bitmask (r9 LDS version). Sub-diagonal tiles write their zero
// words directly (replaces the 4 MB memset dispatch).
__global__ __launch_bounds__(64) void k6_mask(
    const float* __restrict__ tsb, u64* __restrict__ mask) {
    const int img = blockIdx.z;
    const int tid = threadIdx.x;
    if (blockIdx.x < blockIdx.y) {       // no j>i pairs here: write zeros
        const int i = blockIdx.y * 64 + tid;
        mask[((size_t)img * KPRE + i) * 32 + blockIdx.x] = 0ull;
        return;
    }
    const int j0 = blockIdx.x * 64;
    const int i0 = blockIdx.y * 64;
    __shared__ float4 cb[64];
    __shared__ float ca[64];
    float4 c = reinterpret_cast<const float4*>(tsb)[(size_t)img * KPRE + j0 + tid];
    cb[tid] = c;
    ca[tid] = (c.z - c.x) * (c.w - c.y);
    __syncthreads();
    const int i = i0 + tid;
    float4 r = reinterpret_cast<const float4*>(tsb)[(size_t)img * KPRE + i];
    float ra = (r.z - r.x) * (r.w - r.y);
    u64 bits = 0ull;
#pragma unroll 8
    for (int jj = 0; jj < 64; ++jj) {
        int j = j0 + jj;
        float4 cc = cb[jj];
        float wv = fmaxf(fminf(r.z, cc.z) - fmaxf(r.x, cc.x), 0.0f);
        float hv = fmaxf(fminf(r.w, cc.w) - fmaxf(r.y, cc.y), 0.0f);
        float inter = wv * hv;
        float iou = inter / ((ra + ca[jj]) - inter);   // NaN compares false, like jnp
        if ((iou > NMS_T) && (j > i)) bits |= (1ull << jj);
    }
    mask[((size_t)img * KPRE + i) * 32 + (j0 >> 6)] = bits;
}

// K7+K8 fused (validated bit-exact in r10's mega P7): greedy NMS with SALU
// serial chain, double-buffered LDS DMA, b128 apply, early exit at DETS kept;
// then in the SAME wave: popcount-prefix select of the first 100 kept rows
// (tsc descending in s + XLA tie-break => exact top_k equivalence).
__device__ __forceinline__ u64 rdlane64(u64 v, int l) {
    u32 lo = (u32)__builtin_amdgcn_readlane((int)(u32)v, l);
    u32 hi = (u32)__builtin_amdgcn_readlane((int)(u32)(v >> 32), l);
    return ((u64)hi << 32) | lo;
}

__device__ __forceinline__ void g2l16(const void* g, void* l) {
    __builtin_amdgcn_global_load_lds(
        (const __attribute__((address_space(1))) void*)g,
        (__attribute__((address_space(3))) void*)l, 16, 0, 0);
}

__global__ __launch_bounds__(64) void k7_nms_sel(
    const u64* __restrict__ mask, const u32* __restrict__ tvl,
    const float* __restrict__ tsc, const float* __restrict__ tbox,
    const int* __restrict__ tlb, float* __restrict__ out) {
    __shared__ u64 smem[4096];           // 2 x 16 KB double buffer
    const int img = blockIdx.x;
    const int lane = threadIdx.x;
    const int lg = lane >> 4;
    const u64* mrow = mask + (size_t)img * KPRE * 32;

    u64 accx = 0ull, accy = 0ull, rp = 0ull;
    for (int w = 0; w < 32; ++w) {
        bool tv = tvl[(size_t)img * KPRE + w * 64 + lane] != 0u;
        u64 iw = ~__ballot(tv);
        if (w == 0) rp = iw;
        if ((lane & 15) == (w >> 1)) { if (w & 1) accy = iw; else accx = iw; }
    }

    {
        const char* gsrc = (const char*)mrow + (size_t)lane * 16;
#pragma unroll
        for (int t = 0; t < 16; ++t)
            g2l16(gsrc + (size_t)t * 1024, (char*)smem + (size_t)t * 1024);
    }
    u64 diag = mrow[(size_t)lane * 32];

    u32 tk = 0;
    int bcut = 31;

#pragma unroll 1
    for (int b = 0; b < 32; ++b) {
        const size_t base32 = (size_t)b * 2048;
        const u64* cbuf = smem + (size_t)(b & 1) * 2048;

        u64 diagn = 0ull;
        if (b + 1 < 32) {
            diagn = mrow[base32 + 2048 + (size_t)lane * 32 + (b + 1)];
            const char* gsrc = (const char*)(mrow + base32 + 2048) + (size_t)lane * 16;
            char* nb_l = (char*)(smem + (size_t)((b + 1) & 1) * 2048);
#pragma unroll
            for (int t = 0; t < 16; ++t)
                g2l16(gsrc + (size_t)t * 1024, nb_l + (size_t)t * 1024);
        }

        u64 A = rp;
#pragma unroll
        for (int u = 0; u < 64; ++u) {
            u64 row = rdlane64(diag, u);
            if (!((A >> u) & 1ull)) A |= row;
        }
        const u64 keptw = ~A;

        if (b + 1 < 32) asm volatile("s_waitcnt vmcnt(17)" ::: "memory");
        else            asm volatile("s_waitcnt vmcnt(0)" ::: "memory");

#define LDV(K) u64x2 v##K = *(const u64x2*)&cbuf[128 * (K) + 2 * lane];
#define PRV(K) { u32 nib = (u32)(keptw >> (4 * (K))) & 15u; \
                 u32 kb = (nib >> lg) & 1u; \
                 accx |= kb ? v##K.x : 0ull; accy |= kb ? v##K.y : 0ull; }
        LDV(0) LDV(1) LDV(2) LDV(3)
        LDV(4) LDV(5) LDV(6) LDV(7)     PRV(0) PRV(1) PRV(2) PRV(3)
        LDV(8) LDV(9) LDV(10) LDV(11)   PRV(4) PRV(5) PRV(6) PRV(7)
        LDV(12) LDV(13) LDV(14) LDV(15) PRV(8) PRV(9) PRV(10) PRV(11)
        PRV(12) PRV(13) PRV(14) PRV(15)
#undef LDV
#undef PRV

        tk += (u32)__popcll(keptw);
        if (tk >= (u32)DETS) { bcut = b; break; }

        const int nb2 = b + 1;
        if (nb2 < 32) {
            u64 asel = (nb2 & 1) ? accy : accx;
            const int sl = (nb2 >> 1) & 15;
            rp = rdlane64(asel, sl) | rdlane64(asel, sl + 16) |
                 rdlane64(asel, sl + 32) | rdlane64(asel, sl + 48);
        }
        diag = diagn;
    }

    asm volatile("s_waitcnt vmcnt(0)" ::: "memory");   // drain in-flight DMA

    accx |= __shfl_xor(accx, 16); accx |= __shfl_xor(accx, 32);
    accy |= __shfl_xor(accy, 16); accy |= __shfl_xor(accy, 32);

    // k8: lane w (<32) gets keep word w via shfl; gate by bcut
    u64 mxv = __shfl(accx, (lane >> 1) & 15);
    u64 myv = __shfl(accy, (lane >> 1) & 15);
    u64 kw = (lane & 1) ? ~myv : ~mxv;
    if (lane >= 32 || lane > bcut) kw = 0ull;

    u32 cnt = (u32)__popcll(kw);
    u32 inc = cnt;
#pragma unroll
    for (int o = 1; o < 64; o <<= 1) { u32 t = __shfl_up(inc, o); if (lane >= o) inc += t; }
    const u32 excl = inc - cnt;
    const u32 total = (u32)__shfl(inc, 63);

    float* ob0 = out + (size_t)img * DETS * 4;
    float* os0 = out + (size_t)BIMG * DETS * 4 + (size_t)img * DETS;
    float* ol0 = out + (size_t)BIMG * DETS * 5 + (size_t)img * DETS;

#pragma unroll
    for (int t = 0; t < 2; ++t) {
        u32 r = (u32)lane + (u32)t * 64;
        if (r < DETS && r >= total) {
            reinterpret_cast<float4*>(ob0)[r] = make_float4(0.f, 0.f, 0.f, 0.f);
            os0[r] = 0.0f;
            ol0[r] = -1.0f;
        }
    }
    u64 w = kw;
    u32 r = excl;
    while (w != 0ull && r < DETS) {
        int p = __ffsll((unsigned long long)w) - 1;
        w &= (w - 1ull);
        u32 s = (u32)lane * 64u + (u32)p;
        reinterpret_cast<float4*>(ob0)[r] =
            reinterpret_cast<const float4*>(tbox)[(size_t)img * KPRE + s];
        os0[r] = tsc[(size_t)img * KPRE + s];
        ol0[r] = (float)tlb[(size_t)img * KPRE + s];
        ++r;
    }
}

extern "C" void kernel_launch(void* const* d_in, const int* in_sizes, int n_in,
                              void* d_out, int out_size, void* d_ws, size_t ws_size,
                              hipStream_t stream) {
    const float* logits = (const float*)d_in[0];
    const float* reg    = (const float*)d_in[1];
    const float* props  = (const float*)d_in[2];
    const int*   imh    = (const int*)d_in[3];
    const int*   imw    = (const int*)d_in[4];
    float* out = (float*)d_out;
    char* ws = (char*)d_ws;
    if (ws_size < WS_NEED) return;  // ~16.8 MB needed

    u32* histrep  = (u32*)(ws + HISTREP_OFF);
    u32* bcntrep  = (u32*)(ws + BCNTREP_OFF);
    u32* meta     = (u32*)(ws + META_OFF);
    u32* start    = (u32*)(ws + START_OFF);
    u32* histtot  = (u32*)(ws + HISTTOT_OFF);
    u32* startrep = (u32*)(ws + STARTREP_OFF);
    u64* sel  = (u64*)(ws + SEL_OFF);
    float* tbox = (float*)(ws + TBOX_OFF);
    float* tsb  = (float*)(ws + TSB_OFF);
    float* tsc  = (float*)(ws + TSC_OFF);
    int*   tlb  = (int*)(ws + TLB_OFF);
    u32*   tvl  = (u32*)(ws + TVL_OFF);
    u32*   wlist = (u32*)(ws + WLIST_OFF);
    u32*   cand_ord = (u32*)(ws + UNION_OFF);   // overlaid with mask
    u64*   mask = (u64*)(ws + UNION_OFF);       // fully written by k6 after k3's last read

    hipMemsetAsync(d_ws, 0, ZERO_BYTES, stream);  // histrep, bcntrep, meta

    k1_score_hist<<<BIMG * NPROP / 4, 256, 0, stream>>>(logits, reg, props, imh, imw,
                                                        histrep, cand_ord);
    k2_scan<<<BIMG, 256, 0, stream>>>(histrep, histtot, start, startrep, meta, wlist);
    k3_compact<<<(BIMG * MCAND) / 256, 256, 0, stream>>>(cand_ord, startrep, meta, bcntrep, sel);
    k4_sortseg<<<dim3(64, BIMG), 256, 0, stream>>>(histtot, start, meta, wlist, sel);
    k5_gather<<<BIMG, 256, 0, stream>>>(sel, reg, props, imh, imw, tbox, tsb, tsc, tlb, tvl);
    k6_mask<<<dim3(32, 32, BIMG), 64, 0, stream>>>(tsb, mask);
    k7_nms_sel<<<BIMG, 64, 0, stream>>>(mask, tvl, tsc, tbox, tlb, out);
}